// Round 8
// baseline (496.325 us; speedup 1.0000x reference)
//
#include <hip/hip_runtime.h>
#include <hip/hip_bf16.h>
#include <cstdint>
#include <cstddef>

typedef __fp16 f16_t;
typedef __attribute__((ext_vector_type(8))) __fp16 f16x8;
typedef __attribute__((ext_vector_type(4))) __fp16 f16x4;
typedef __attribute__((ext_vector_type(2))) __fp16 h2_t;
typedef __attribute__((ext_vector_type(4))) float floatx4;
typedef __attribute__((ext_vector_type(16))) float floatx16;

// ---------------------------------------------------------------- helpers
__device__ __forceinline__ void async_copy_16B(const void* g, void* l) {
  __builtin_amdgcn_global_load_lds(
      (const __attribute__((address_space(1))) void*)g,
      (__attribute__((address_space(3))) void*)l, 16, 0, 0);
}

// ---------------------------------------------------------------- prep
// Fused: cast x/w_in/w_out to f16 (5242880 float4s) and build packed f16
// weight-pair table wp[p][c], p=0..127:
//   p<126 : (w[p], w[p+1]) ; p==126 : (w[126], 0) ; p==127 : (0, w[0])
__global__ __launch_bounds__(256) void prep(
    const float* __restrict__ x, const float* __restrict__ w_in,
    const float* __restrict__ w_out, const float* __restrict__ w_dw,
    f16_t* __restrict__ x_h, f16_t* __restrict__ wi_h,
    f16_t* __restrict__ wo_h, h2_t* __restrict__ wp) {
  const int tid = blockIdx.x * 256 + threadIdx.x;
  if (tid < 5242880) {
    const float* src;
    f16_t* dst;
    int off;
    if (tid < 2097152) {
      src = x; dst = x_h; off = tid;
    } else if (tid < 4194304) {
      src = w_in; dst = wi_h; off = tid - 2097152;
    } else {
      src = w_out; dst = wo_h; off = tid - 4194304;
    }
    const float4 v = *(const float4*)(src + (size_t)off * 4);
    f16x4 o;
    o.x = (f16_t)v.x; o.y = (f16_t)v.y; o.z = (f16_t)v.z; o.w = (f16_t)v.w;
    *(f16x4*)(dst + (size_t)off * 4) = o;
  } else {
    const int idx = tid - 5242880;
    if (idx < 128 * 4096) {
      const int p = idx >> 12;
      const int c = idx & 4095;
      float a, b;
      if (p < 126) {
        a = w_dw[c * 127 + p]; b = w_dw[c * 127 + p + 1];
      } else if (p == 126) {
        a = w_dw[c * 127 + 126]; b = 0.f;
      } else {
        a = 0.f; b = w_dw[c * 127 + 0];
      }
      h2_t w;
      w.x = (f16_t)a; w.y = (f16_t)b;
      wp[idx] = w;
    }
  }
}

// ---------------------------------------------------------------- GEMM1
// 32x32x16-MFMA version of the R3 schedule. 256x256 tile, BK=64, 8 waves
// (2M x 4N), wave tile 128x64 = 4x2 tiles of 32x32 -> acc floatx16[4][2].
// ONE phase per K-tile: stage(t+1 -> d^1) -> vmcnt(8) -> barrier ->
// 24 ds_read_b128 + 32 MFMA/wave -> barrier. 128 KiB LDS double buffer.
//
// Fragment-major LDS (R5-verified approach): each 32x16 fragment = 1 KB
// contiguous; ds_read_b128 at fragbase + lane*16 (conflict-free). Reader
// lane l expects (row = l&31, k8 = l>>5); global_load_lds writes LDS
// linearly in lane order, so the global source uses the same mapping:
//   chunk q: frag = q>>6 (= rb*4+ks), i = q&63
//   row = rb*32 + (i&31), col = k0 + ks*16 + (i>>5)*8 ; LDS off = q*16.
// C/D layout (guide-verified m74/m101): col = lane&31,
//   row = (reg&3) + 8*(reg>>2) + 4*(lane>>5), reg 0..15.
//
// bofs: grid split into two 512-block launches (instrumentation: makes
// conv_gate / gemmN128 / prep visible in top-5) — mapping unchanged.
__global__ __launch_bounds__(512, 2) void gemm256_x32(
    const f16_t* __restrict__ A, const f16_t* __restrict__ B,
    f16_t* __restrict__ C, int M, int N, int K, int bofs) {
  extern __shared__ char smem[];
  const int t = threadIdx.x;
  const int lane = t & 63;
  const int wave = t >> 6;
  const int wm = wave >> 2;  // 0..1 : 128-row half
  const int wn = wave & 3;   // 0..3 : 64-col strip

  // quad-rect XCD swizzle (verified: FETCH 270->98 MB). Bijective, 1024.
  const int bid = blockIdx.x + bofs;
  const int xcd = bid & 7;
  const int l = bid >> 3;      // 0..127
  const int quad = l >> 5;     // 0..3
  const int qm = (l >> 3) & 3; // 0..3
  const int qn = l & 7;        // 0..7
  const int m0 = ((xcd >> 1) * 8 + (quad >> 1) * 4 + qm) * 256;
  const int n0 = ((xcd & 1) * 16 + (quad & 1) * 8 + qn) * 256;

  auto stageTile = [&](int d, int k0) {
    char* base = smem + d * 65536;
#pragma unroll
    for (int u = 0; u < 4; ++u) {
      const int q = u * 512 + t;
      const int frag = q >> 6;  // rb*4 + ks
      const int i = q & 63;
      const int row = (frag >> 2) * 32 + (i & 31);
      const int col = (frag & 3) * 16 + (i >> 5) * 8;
      async_copy_16B(A + (size_t)(m0 + row) * K + k0 + col, base + q * 16);
    }
#pragma unroll
    for (int u = 0; u < 4; ++u) {
      const int q = u * 512 + t;
      const int frag = q >> 6;  // nb*4 + ks
      const int i = q & 63;
      const int row = (frag >> 2) * 32 + (i & 31);
      const int col = (frag & 3) * 16 + (i >> 5) * 8;
      async_copy_16B(B + (size_t)(n0 + row) * K + k0 + col,
                     base + 32768 + q * 16);
    }
  };
  auto ldA = [&](int d, int rb, int ks) -> f16x8 {
    return *(const f16x8*)(smem + d * 65536 + (rb * 4 + ks) * 1024 +
                           lane * 16);
  };
  auto ldB = [&](int d, int nb, int ks) -> f16x8 {
    return *(const f16x8*)(smem + d * 65536 + 32768 + (nb * 4 + ks) * 1024 +
                           lane * 16);
  };

  floatx16 acc[4][2] = {};
  const int kT = K / 64;  // 16

  stageTile(0, 0);
  for (int tt = 0; tt < kT; ++tt) {
    const int d = tt & 1;
    if (tt + 1 < kT) {
      stageTile(d ^ 1, (tt + 1) * 64);  // d^1 dead since tt-1's close bar
      asm volatile("s_waitcnt vmcnt(8)" ::: "memory");  // tile tt landed
    } else {
      asm volatile("s_waitcnt vmcnt(0)" ::: "memory");
    }
    __builtin_amdgcn_s_barrier();

    f16x8 bfr[2][4];
#pragma unroll
    for (int nb = 0; nb < 2; ++nb)
#pragma unroll
      for (int ks = 0; ks < 4; ++ks)
        bfr[nb][ks] = ldB(d, wn * 2 + nb, ks);
    __builtin_amdgcn_s_setprio(1);
#pragma unroll
    for (int ks = 0; ks < 4; ++ks)
#pragma unroll
      for (int i = 0; i < 4; ++i) {
        const f16x8 af = ldA(d, wm * 4 + i, ks);
#pragma unroll
        for (int j = 0; j < 2; ++j)
          acc[i][j] = __builtin_amdgcn_mfma_f32_32x32x16_f16(
              af, bfr[j][ks], acc[i][j], 0, 0, 0);
      }
    __builtin_amdgcn_s_setprio(0);
    __builtin_amdgcn_s_barrier();  // reads of d done before t+1 stages d
  }

  // C/D: col = lane&31, row = (reg&3) + 8*(reg>>2) + 4*(lane>>5)
  const int rl4 = (lane >> 5) * 4;
  const int cl = lane & 31;
#pragma unroll
  for (int i = 0; i < 4; ++i)
#pragma unroll
    for (int j = 0; j < 2; ++j)
#pragma unroll
      for (int r = 0; r < 16; ++r) {
        const int row =
            m0 + wm * 128 + i * 32 + (r & 3) + 8 * (r >> 2) + rl4;
        const int col = n0 + wn * 64 + j * 32 + cl;
        C[(size_t)row * N + col] = (f16_t)acc[i][j][r];
      }
}

// ---------------------------------------------------------------- GEMM2
// 32x32x16 version of the R3 out-projection. BM=256, BN=128, BK=64,
// 512 thr, 8 waves (2M x 4N), wave tile 128x32 = 4 tiles of 32x32 ->
// acc floatx16[4] (64 AGPR). 96 KiB LDS double buffer (1 block/CU),
// 1-phase/tile, counted vmcnt(6). Grid = 256 blocks (32m x 8n),
// XCD-mapped. Same fragment-major LDS as GEMM1 (A 32 frags, B 16 frags).
__global__ __launch_bounds__(512, 2) void gemmN128_x32(
    const f16_t* __restrict__ A, const f16_t* __restrict__ B,
    float* __restrict__ C, int M, int N, int K) {
  extern __shared__ char smem[];
  const int t = threadIdx.x;
  const int lane = t & 63;
  const int wave = t >> 6;
  const int wm = wave >> 2;  // 0..1
  const int wn = wave & 3;   // 0..3

  const int bid = blockIdx.x;
  const int xcd = bid & 7;
  const int l = bid >> 3;                     // 0..31
  const int m0 = (xcd * 4 + (l >> 3)) * 256;  // 32 m-tiles
  const int n0 = (l & 7) * 128;               // 8 n-tiles

  auto stageTile = [&](int d, int k0) {
    char* base = smem + d * 49152;
#pragma unroll
    for (int u = 0; u < 4; ++u) {  // A: 2048 chunks
      const int q = u * 512 + t;
      const int frag = q >> 6;
      const int i = q & 63;
      const int row = (frag >> 2) * 32 + (i & 31);
      const int col = (frag & 3) * 16 + (i >> 5) * 8;
      async_copy_16B(A + (size_t)(m0 + row) * K + k0 + col, base + q * 16);
    }
#pragma unroll
    for (int u = 0; u < 2; ++u) {  // B: 1024 chunks
      const int q = u * 512 + t;
      const int frag = q >> 6;  // nb*4 + ks, nb 0..3
      const int i = q & 63;
      const int row = (frag >> 2) * 32 + (i & 31);
      const int col = (frag & 3) * 16 + (i >> 5) * 8;
      async_copy_16B(B + (size_t)(n0 + row) * K + k0 + col,
                     base + 32768 + q * 16);
    }
  };
  auto ldA = [&](int d, int rb, int ks) -> f16x8 {
    return *(const f16x8*)(smem + d * 49152 + (rb * 4 + ks) * 1024 +
                           lane * 16);
  };
  auto ldB = [&](int d, int nb, int ks) -> f16x8 {
    return *(const f16x8*)(smem + d * 49152 + 32768 + (nb * 4 + ks) * 1024 +
                           lane * 16);
  };

  floatx16 acc[4] = {};
  const int kT = K / 64;  // 64

  stageTile(0, 0);
  for (int tt = 0; tt < kT; ++tt) {
    const int d = tt & 1;
    if (tt + 1 < kT) {
      stageTile(d ^ 1, (tt + 1) * 64);
      asm volatile("s_waitcnt vmcnt(6)" ::: "memory");  // tile tt landed
    } else {
      asm volatile("s_waitcnt vmcnt(0)" ::: "memory");
    }
    __builtin_amdgcn_s_barrier();

    f16x8 bfr[4];
#pragma unroll
    for (int ks = 0; ks < 4; ++ks) bfr[ks] = ldB(d, wn, ks);
    __builtin_amdgcn_s_setprio(1);
#pragma unroll
    for (int ks = 0; ks < 4; ++ks)
#pragma unroll
      for (int i = 0; i < 4; ++i) {
        const f16x8 af = ldA(d, wm * 4 + i, ks);
        acc[i] = __builtin_amdgcn_mfma_f32_32x32x16_f16(
            af, bfr[ks], acc[i], 0, 0, 0);
      }
    __builtin_amdgcn_s_setprio(0);
    __builtin_amdgcn_s_barrier();
  }

  const int rl4 = (lane >> 5) * 4;
  const int cl = lane & 31;
#pragma unroll
  for (int i = 0; i < 4; ++i)
#pragma unroll
    for (int r = 0; r < 16; ++r) {
      const int row = m0 + wm * 128 + i * 32 + (r & 3) + 8 * (r >> 2) + rl4;
      const int col = n0 + wn * 32 + cl;
      C[(size_t)row * N + col] = acc[i][r];
    }
}

// ---------------------------------------------------------------- conv+gate
// (R7 rolling-strip version, kept verbatim — passed, neutral perf.)
#define CONV_L 128
#define CPAIRS 127  // (CONV_L + 126) / 2

__global__ __launch_bounds__(256) void conv_gate(
    const f16_t* __restrict__ vg, const h2_t* __restrict__ wp,
    const float* __restrict__ b_dw, f16_t* __restrict__ y) {
  __shared__ uint32_t vtp[CPAIRS * 64];  // 32.5 KB
  __shared__ uint32_t wpl[128 * 64];     // 32 KB
  const int t = threadIdx.x;
  const int lane = t & 63;
  const int wave = t >> 6;
  const int c0 = blockIdx.x * 64;
  const int b = blockIdx.y >> 2;   // batch
  const int lh = blockIdx.y & 3;   // 1024-l strip

  // stage weight pairs wp[p][c0..c0+63] -> wpl ONCE (global->LDS DMA)
#pragma unroll
  for (int it = 0; it < 8; ++it) {
    const int q = it * 256 + t;
    async_copy_16B(wp + (size_t)(q >> 4) * 4096 + c0 + (q & 15) * 4,
                   wpl + q * 4);
  }

  const int c = c0 + lane;
  const float bias = b_dw[c];
  const uint32_t* vbase = vtp + wave * 16 * 64 + lane;
  const uint32_t* wbase = wpl + lane;

  for (int j = 0; j < 8; ++j) {
    const int l0 = lh * 1024 + j * CONV_L;

    for (int q = t; q < CPAIRS * 8; q += 256) {
      const int m = q >> 3;
      const int oc = (q & 7) * 8;
      const int le = l0 - 126 + 2 * m;  // always even
      uint4 a = make_uint4(0u, 0u, 0u, 0u);
      uint4 bb = make_uint4(0u, 0u, 0u, 0u);
      if (le >= 0) {
        const size_t base = (size_t)(b * 4096 + le) * 8192 + c0 + oc;
        a = *(const uint4*)(vg + base);
        bb = *(const uint4*)(vg + base + 8192);
      }
      const uint32_t aw[4] = {a.x, a.y, a.z, a.w};
      const uint32_t bw[4] = {bb.x, bb.y, bb.z, bb.w};
      uint32_t dw[8];
#pragma unroll
      for (int i = 0; i < 4; ++i) {
        dw[2 * i] = (aw[i] & 0xFFFFu) | (bw[i] << 16);
        dw[2 * i + 1] = (aw[i] >> 16) | (bw[i] & 0xFFFF0000u);
      }
      uint32_t* dst = vtp + q * 8;
      *(uint4*)dst = make_uint4(dw[0], dw[1], dw[2], dw[3]);
      *(uint4*)(dst + 4) = make_uint4(dw[4], dw[5], dw[6], dw[7]);
    }

    const int lb = l0 + wave * 32;
    const f16_t* gp = vg + (size_t)(b * 4096 + lb) * 8192 + 4096 + c;
    f16_t gvals[32];
#pragma unroll
    for (int i = 0; i < 32; ++i) gvals[i] = gp[(size_t)i * 8192];

    __syncthreads();

    float acc[32];
#pragma unroll
    for (int i = 0; i < 32; ++i) acc[i] = bias;

    h2_t ring[17];
#pragma unroll
    for (int m = 0; m < 17; ++m)
      ring[m] = __builtin_bit_cast(h2_t, vbase[m * 64]);

    {
      const h2_t w0 = __builtin_bit_cast(h2_t, wbase[127 * 64]);
#pragma unroll
      for (int h = 0; h < 16; ++h)
        acc[2 * h + 1] =
            __builtin_amdgcn_fdot2(w0, ring[h], acc[2 * h + 1], false);
    }

#pragma unroll
    for (int k = 0; k < 64; ++k) {
      const h2_t we = __builtin_bit_cast(h2_t, wbase[(2 * k) * 64]);
#pragma unroll
      for (int h = 0; h < 16; ++h)
        acc[2 * h] =
            __builtin_amdgcn_fdot2(we, ring[(k + h) % 17], acc[2 * h], false);
      if (k < 63) {
        const h2_t wo = __builtin_bit_cast(h2_t, wbase[(2 * k + 1) * 64]);
#pragma unroll
        for (int h = 0; h < 16; ++h)
          acc[2 * h + 1] = __builtin_amdgcn_fdot2(wo, ring[(k + 1 + h) % 17],
                                                  acc[2 * h + 1], false);
        if (k < 62)
          ring[k % 17] = __builtin_bit_cast(h2_t, vbase[(17 + k) * 64]);
      }
    }

    f16_t* yp = y + (size_t)(b * 4096 + lb) * 4096 + c;
#pragma unroll
    for (int i = 0; i < 32; ++i) {
      const float gv = (float)gvals[i];
      const float v = acc[i];
      const float sv = v / (1.f + __expf(-v));
      const float sg = gv / (1.f + __expf(-gv));
      yp[(size_t)i * 4096] = (f16_t)(sv * sg);
    }

    __syncthreads();
  }
}

// ---------------------------------------------------------------- launch
extern "C" void kernel_launch(void* const* d_in, const int* in_sizes, int n_in,
                              void* d_out, int out_size, void* d_ws,
                              size_t ws_size, hipStream_t stream) {
  const float* x     = (const float*)d_in[0];  // [2,4096,1024]
  const float* w_in  = (const float*)d_in[1];  // [8192,1024]
  const float* w_dw  = (const float*)d_in[2];  // [4096,127]
  const float* b_dw  = (const float*)d_in[3];  // [4096]
  const float* w_out = (const float*)d_in[4];  // [1024,4096]
  float* out = (float*)d_out;                  // [2,4096,1024]

  char* p = (char*)d_ws;
  f16_t* x_h  = (f16_t*)p; p += (size_t)8192 * 1024 * 2;
  f16_t* wi_h = (f16_t*)p; p += (size_t)8192 * 1024 * 2;
  f16_t* wo_h = (f16_t*)p; p += (size_t)1024 * 4096 * 2;
  h2_t*  wp   = (h2_t*)p;  p += (size_t)128 * 4096 * 4;
  f16_t* vg   = (f16_t*)p; p += (size_t)8192 * 8192 * 2;
  f16_t* y    = (f16_t*)p; p += (size_t)8192 * 4096 * 2;

  // fused casts + packed weight-pair build
  prep<<<22528, 256, 0, stream>>>(x, w_in, w_out, w_dw, x_h, wi_h, wo_h, wp);

  // vg[8192,8192] = x[8192,1024] @ w_in[8192,1024]^T
  // 32x32x16 MFMA, R3 schedule; split into 2 launches (instrumentation)
  hipFuncSetAttribute(reinterpret_cast<const void*>(gemm256_x32),
                      hipFuncAttributeMaxDynamicSharedMemorySize, 131072);
  gemm256_x32<<<512, 512, 131072, stream>>>(x_h, wi_h, vg, 8192, 8192, 1024,
                                            0);
  gemm256_x32<<<512, 512, 131072, stream>>>(x_h, wi_h, vg, 8192, 8192, 1024,
                                            512);

  // y = silu(causal_dwconv(v)+b) * silu(g)  (rolling-strip, 512 blocks)
  conv_gate<<<dim3(64, 8), 256, 0, stream>>>(vg, wp, b_dw, y);

  // out[8192,1024] = y[8192,4096] @ w_out[1024,4096]^T (32x32x16 MFMA)
  hipFuncSetAttribute(reinterpret_cast<const void*>(gemmN128_x32),
                      hipFuncAttributeMaxDynamicSharedMemorySize, 98304);
  gemmN128_x32<<<256, 512, 98304, stream>>>(y, wo_h, out, 8192, 1024, 4096);
}